// Round 2
// baseline (1152.797 us; speedup 1.0000x reference)
//
#include <hip/hip_runtime.h>

// SuppAlignLayer: 4-level ROI Align, B=2, C=256, N=512, OUT=7, SR=2, fp32.
// R2 strategy: block per (roi, level). Channels processed in 64 stages of 4:
// each wave stages one channel's ROI bounding-box region into LDS via
// coalesced row loads; 196 compute threads (4 channels x 49 bins) hold their
// bin's 16 bilinear (offset, weight) pairs in registers (computed once,
// reused across all stages) and do 16 ds_read_b32 + FMA per output.
// Output stores are perfectly coalesced (out[r*12544 + stage*196 + t]).

#define OUT_ROI_STRIDE 12544
#define OUT_LVL_STRIDE 12845056

template<int H, int W, int SHIFT, int MAXR>
__global__ __launch_bounds__(256)
void roi_align_lvl(const float* __restrict__ feat,
                   const float* __restrict__ boxes,
                   float* __restrict__ out)
{
    constexpr int RSZ = MAXR * MAXR;
    __shared__ float sreg[4 * RSZ];

    const int r    = blockIdx.x;     // roi 0..1023
    const int t    = threadIdx.x;
    const int lane = t & 63;
    const int wv   = t >> 6;         // wave 0..3 = staged channel sub-index
    constexpr float scale = 1.0f / (float)(1 << SHIFT);

    const float bx1 = boxes[r * 4 + 0] * scale;
    const float by1 = boxes[r * 4 + 1] * scale;
    const float bx2 = boxes[r * 4 + 2] * scale;
    const float by2 = boxes[r * 4 + 3] * scale;
    const float rw7 = fmaxf(bx2 - bx1, 1.0f) * (1.0f / 7.0f);
    const float rh7 = fmaxf(by2 - by1, 1.0f) * (1.0f / 7.0f);

    const float Hm1 = (float)(H - 1), Wm1 = (float)(W - 1);

    // Region bounds from first/last sample (coords monotone in k).
    // __fmaf_rn here and in metadata below -> bitwise-identical coords,
    // so region-relative offsets are exactly consistent.
    const int ry0 = (int)fminf(fmaxf(__fmaf_rn(rh7, 0.25f, by1), 0.0f), Hm1);
    const int rx0 = (int)fminf(fmaxf(__fmaf_rn(rw7, 0.25f, bx1), 0.0f), Wm1);
    const int ryM = (int)fminf(fmaxf(__fmaf_rn(rh7, 6.75f, by1), 0.0f), Hm1);
    const int rxM = (int)fminf(fmaxf(__fmaf_rn(rw7, 6.75f, bx1), 0.0f), Wm1);
    const int RH = min(ryM + 1, H - 1) - ry0 + 1;   // <= MAXR by construction
    const int RW = min(rxM + 1, W - 1) - rx0 + 1;   // <= MAXR <= 62 < 64

    // Per-thread bin metadata (valid for t < 196), kept in registers.
    const int g   = t / 49;          // channel sub-index 0..3
    const int bin = t - g * 49;
    const int ph  = bin / 7;
    const int pw  = bin - ph * 7;

    int4   offs[4];
    float4 wts[4];
    if (t < 196) {
        #pragma unroll
        for (int sub = 0; sub < 4; ++sub) {
            const int ky = 2 * ph + (sub >> 1);
            const int kx = 2 * pw + (sub & 1);
            const float gy = ((float)ky + 0.5f) * 0.5f;   // exact
            const float gx = ((float)kx + 0.5f) * 0.5f;
            const float ys = __fmaf_rn(rh7, gy, by1);
            const float xs = __fmaf_rn(rw7, gx, bx1);
            const bool vy = (ys >= -1.0f) && (ys <= (float)H);
            const bool vx = (xs >= -1.0f) && (xs <= (float)W);
            const float yc = fminf(fmaxf(ys, 0.0f), Hm1);
            const float xc = fminf(fmaxf(xs, 0.0f), Wm1);
            const int y0 = (int)yc;                       // trunc == floor (>=0)
            const int x0 = (int)xc;
            const int dy = (y0 + 1 <= H - 1) ? 1 : 0;
            const int dx = (x0 + 1 <= W - 1) ? 1 : 0;
            const float ly = yc - (float)y0, lx = xc - (float)x0;
            const float hy = 1.0f - ly,      hx = 1.0f - lx;
            const float vm = (vy && vx) ? 0.25f : 0.0f;   // fold 2x2 mean
            const int o00 = (y0 - ry0) * RW + (x0 - rx0);
            offs[sub] = make_int4(o00, o00 + dx, o00 + dy * RW, o00 + dy * RW + dx);
            wts[sub]  = make_float4(hy * hx * vm, hy * lx * vm,
                                    ly * hx * vm, ly * lx * vm);
        }
    }

    const int b = r >> 9;
    const float* base = feat + (size_t)b * (size_t)(256 * H * W);
    const float* stage_base = base + (size_t)wv * (size_t)(H * W)
                                   + (size_t)(ry0 * W + rx0);
    float* oline = out + (size_t)r * OUT_ROI_STRIDE;
    float* swr = sreg + wv * RSZ;
    const float* __restrict__ sg = sreg + g * RSZ;  // only deref'd when t<196

    for (int s = 0; s < 64; ++s) {
        // ---- stage: wave wv loads channel s*4+wv's region, coalesced rows
        const float* p = stage_base + (size_t)(s * 4) * (size_t)(H * W);
        if (lane < RW) {
            for (int rr = 0; rr < RH; ++rr)
                swr[rr * RW + lane] = p[rr * W + lane];
        }
        __syncthreads();
        // ---- compute: 196 threads, one output each, metadata in registers
        if (t < 196) {
            float acc = 0.0f;
            #pragma unroll
            for (int sub = 0; sub < 4; ++sub) {
                acc += sg[offs[sub].x] * wts[sub].x;
                acc += sg[offs[sub].y] * wts[sub].y;
                acc += sg[offs[sub].z] * wts[sub].z;
                acc += sg[offs[sub].w] * wts[sub].w;
            }
            oline[s * 196 + t] = acc;   // coalesced
        }
        __syncthreads();
    }
}

extern "C" void kernel_launch(void* const* d_in, const int* in_sizes, int n_in,
                              void* d_out, int out_size, void* d_ws, size_t ws_size,
                              hipStream_t stream) {
    const float* f0    = (const float*)d_in[0];
    const float* f1    = (const float*)d_in[1];
    const float* f2    = (const float*)d_in[2];
    const float* f3    = (const float*)d_in[3];
    const float* boxes = (const float*)d_in[4];
    float* out = (float*)d_out;

    roi_align_lvl<200, 304, 2, 62><<<1024, 256, 0, stream>>>(f0, boxes, out);
    roi_align_lvl<100, 152, 3, 32><<<1024, 256, 0, stream>>>(f1, boxes, out + (size_t)OUT_LVL_STRIDE);
    roi_align_lvl< 50,  76, 4, 17><<<1024, 256, 0, stream>>>(f2, boxes, out + 2 * (size_t)OUT_LVL_STRIDE);
    roi_align_lvl< 25,  38, 5, 10><<<1024, 256, 0, stream>>>(f3, boxes, out + 3 * (size_t)OUT_LVL_STRIDE);
}